// Round 2
// baseline (531.017 us; speedup 1.0000x reference)
//
#include <hip/hip_runtime.h>
#include <hip/hip_bf16.h>

#define TOKENS   512
#define HIDDEN   2880
#define INTER    2880
#define NEXP     8
#define GUP_ROWS (2*INTER)   // 5760
#define NPAIR    2048

#define BM 320
#define BN 160
#define BK 32
#define NK (HIDDEN/BK)       // 90
#define NTHREADS 512
#define MT_MAX 7             // worst-case m-tiles per expert (2048/320); extras early-exit

#define A_BUF_BYTES (BM*BK*2)                 // 20480
#define B_BUF_BYTES (BN*BK*2)                 // 10240
#define B_BASE      (2*A_BUF_BYTES)           // 40960
#define LDS_BYTES   (2*A_BUF_BYTES + 2*B_BUF_BYTES)  // 61440

#define UBYTES ((size_t)NPAIR * INTER * 2)    // u bf16 scratch

using bf16x8 = __attribute__((ext_vector_type(8))) short;
using f32x4  = __attribute__((ext_vector_type(4))) float;

__device__ __forceinline__ unsigned cvt2bf(float a, float b) {
  union { __hip_bfloat16 h; unsigned short s; } x, y;
  x.h = __float2bfloat16(a);
  y.h = __float2bfloat16(b);
  return (unsigned)x.s | ((unsigned)y.s << 16);
}

// ---------------- routing ----------------
// meta: [0..7]=counts  [8..15]=offsets(excl prefix)  [16..23]=atomic cursor
__global__ void route_count(const int* __restrict__ eidx, int* __restrict__ meta) {
  __shared__ int cnt[NEXP];
  int t = threadIdx.x;
  if (t < NEXP) cnt[t] = 0;
  __syncthreads();
  for (int a = t; a < NPAIR; a += 256) atomicAdd(&cnt[eidx[a]], 1);
  __syncthreads();
  if (t == 0) {
    int off = 0;
    for (int e = 0; e < NEXP; ++e) {
      meta[e] = cnt[e];
      meta[8 + e] = off;
      meta[16 + e] = off;
      off += cnt[e];
    }
  }
}

__global__ void route_scatter(const int* __restrict__ eidx, int* __restrict__ meta,
                              int* __restrict__ list) {
  int a = blockIdx.x * 256 + threadIdx.x;
  int e = eidx[a];
  int pos = atomicAdd(&meta[16 + e], 1);
  list[pos] = a;   // a = token*4 + slot
}

// ---------------- GEMM1: h = t @ gate_up^T + bias ; u = swiglu(h) ----------------
__global__ __launch_bounds__(NTHREADS, 2)
void gemm1_swiglu(const float* __restrict__ t,
                  const float* __restrict__ gup,
                  const float* __restrict__ gub,
                  const int* __restrict__ meta,
                  const int* __restrict__ list,
                  __hip_bfloat16* __restrict__ u)
{
  const int e  = blockIdx.z;
  const int mt = blockIdx.y;
  const int nt = blockIdx.x;
  const int n_e = meta[e];
  const int m0 = mt * BM;
  if (m0 >= n_e) return;
  const int base = meta[8 + e];

  __shared__ __align__(16) char lds[LDS_BYTES];

  const int tid  = threadIdx.x;
  const int lane = tid & 63;
  const int wid  = tid >> 6;
  const int wm   = wid >> 1;   // 0..3
  const int wn   = wid & 1;    // 0..1

  // --- staging pieces: p<640 -> A(row=p>>1, half=p&1); 640<=p<960 -> B(q=p-640)
  bool pv[2];
  const char* src[2];
  int ldsOff[2], bufMul[2], planeStep[2];
  #pragma unroll
  for (int i = 0; i < 2; ++i) {
    int p = tid + i * NTHREADS;
    pv[i] = (p < 2 * BM + 2 * BN);   // 960 valid pieces
    src[i] = nullptr; ldsOff[i] = 0; bufMul[i] = 0; planeStep[i] = 0;
    if (!pv[i]) continue;
    if (p < 2 * BM) {
      int row = p >> 1, half = p & 1;
      ldsOff[i]   = ((half * 2) * BM + row) * 16;
      bufMul[i]   = A_BUF_BYTES;
      planeStep[i]= BM * 16;
      if (row < n_e - m0) {
        int a = list[base + m0 + row];
        src[i] = (const char*)(t + (size_t)(a >> 2) * HIDDEN + half * 16);
      } else src[i] = nullptr;
    } else {
      int q = p - 2 * BM;
      int col = q >> 1, half = q & 1;
      ldsOff[i]   = B_BASE + ((half * 2) * BN + col) * 16;
      bufMul[i]   = B_BUF_BYTES;
      planeStep[i]= BN * 16;
      src[i] = (const char*)(gup + (size_t)(e * GUP_ROWS + nt * BN + col) * HIDDEN + half * 16);
    }
  }

  float4 rr[2][4];
  auto LOADP = [&](int kt) {
    #pragma unroll
    for (int i = 0; i < 2; ++i) {
      if (!pv[i]) continue;
      if (src[i]) {
        const float4* s = (const float4*)(src[i] + (size_t)kt * 128);
        rr[i][0] = s[0]; rr[i][1] = s[1]; rr[i][2] = s[2]; rr[i][3] = s[3];
      } else {
        float4 z = make_float4(0.f, 0.f, 0.f, 0.f);
        rr[i][0] = z; rr[i][1] = z; rr[i][2] = z; rr[i][3] = z;
      }
    }
  };
  auto STAGEW = [&](int buf) {
    #pragma unroll
    for (int i = 0; i < 2; ++i) {
      if (!pv[i]) continue;
      char* dst = lds + ldsOff[i] + buf * bufMul[i];
      uint4 w0, w1;
      w0.x = cvt2bf(rr[i][0].x, rr[i][0].y); w0.y = cvt2bf(rr[i][0].z, rr[i][0].w);
      w0.z = cvt2bf(rr[i][1].x, rr[i][1].y); w0.w = cvt2bf(rr[i][1].z, rr[i][1].w);
      w1.x = cvt2bf(rr[i][2].x, rr[i][2].y); w1.y = cvt2bf(rr[i][2].z, rr[i][2].w);
      w1.z = cvt2bf(rr[i][3].x, rr[i][3].y); w1.w = cvt2bf(rr[i][3].z, rr[i][3].w);
      *(uint4*)dst = w0;
      *(uint4*)(dst + planeStep[i]) = w1;
    }
  };

  f32x4 acc[5][5];
  #pragma unroll
  for (int fm = 0; fm < 5; ++fm)
    #pragma unroll
    for (int fn = 0; fn < 5; ++fn)
      acc[fm][fn] = f32x4{0.f, 0.f, 0.f, 0.f};

  const int aoffBase = ((lane >> 4) * BM + wm * 80 + (lane & 15)) * 16;
  const int boffBase = B_BASE + ((lane >> 4) * BN + wn * 80 + (lane & 15)) * 16;

  auto COMP = [&](int buf) {
    const char* ab = lds + buf * A_BUF_BYTES + aoffBase;
    const char* bb = lds + buf * B_BUF_BYTES + boffBase;
    bf16x8 af[5], bfr[5];
    #pragma unroll
    for (int f = 0; f < 5; ++f) af[f]  = *(const bf16x8*)(ab + f * 256);
    #pragma unroll
    for (int f = 0; f < 5; ++f) bfr[f] = *(const bf16x8*)(bb + f * 256);
    #pragma unroll
    for (int fm = 0; fm < 5; ++fm)
      #pragma unroll
      for (int fn = 0; fn < 5; ++fn)
        acc[fm][fn] = __builtin_amdgcn_mfma_f32_16x16x32_bf16(af[fm], bfr[fn], acc[fm][fn], 0, 0, 0);
  };

  LOADP(0);
  STAGEW(0);
  __syncthreads();
  for (int kt = 0; kt < NK; ++kt) {
    if (kt + 1 < NK) LOADP(kt + 1);
    COMP(kt & 1);
    if (kt + 1 < NK) STAGEW((kt + 1) & 1);
    __syncthreads();
  }

  // epilogue: +bias, swiglu pairing (even col = glu, odd = lin), write u bf16
  const int colBase = nt * BN + wn * 80 + (lane & 15);
  const int rowBase = m0 + wm * 80 + ((lane >> 4) * 4);
  #pragma unroll
  for (int fm = 0; fm < 5; ++fm) {
    #pragma unroll
    for (int fn = 0; fn < 5; ++fn) {
      const int colg = colBase + fn * 16;
      const float bias = gub[e * GUP_ROWS + colg];
      #pragma unroll
      for (int j = 0; j < 4; ++j) {
        float h = acc[fm][fn][j] + bias;
        float other = __shfl_xor(h, 1, 64);
        int row = rowBase + fm * 16 + j;
        if (!(lane & 1)) {
          float xg = fminf(h, 7.0f);
          float xl = fminf(fmaxf(other, -7.0f), 7.0f);
          float og = xg / (1.0f + __expf(-1.702f * xg));
          float uv = og * (xl + 1.0f);
          if (row < n_e)
            u[(size_t)(base + row) * INTER + (colg >> 1)] = __float2bfloat16(uv);
        }
      }
    }
  }
}

// ---------------- GEMM2: y = u @ down^T + dbias, scatter to out ----------------
__global__ __launch_bounds__(NTHREADS, 2)
void gemm2_down(const __hip_bfloat16* __restrict__ u,
                const float* __restrict__ dwn,
                const float* __restrict__ dbias,
                const int* __restrict__ meta,
                const int* __restrict__ list,
                float* __restrict__ out)
{
  const int e  = blockIdx.z;
  const int mt = blockIdx.y;
  const int nt = blockIdx.x;
  const int n_e = meta[e];
  const int m0 = mt * BM;
  if (m0 >= n_e) return;
  const int base = meta[8 + e];

  __shared__ __align__(16) char lds[LDS_BYTES];

  const int tid  = threadIdx.x;
  const int lane = tid & 63;
  const int wid  = tid >> 6;
  const int wm   = wid >> 1;
  const int wn   = wid & 1;

  // pieces: p<320 -> A row (64B bf16, full BK, 4 planes, no cvt)
  //         320<=p<640 -> B (q=p-320, col=q>>1, half=q&1, 16 f32, cvt, 2 planes)
  bool pv[2]; bool docvt[2];
  const char* src[2];
  int ldsOff[2], bufMul[2], planeStep[2];
  long strideB[2];
  #pragma unroll
  for (int i = 0; i < 2; ++i) {
    int p = tid + i * NTHREADS;
    pv[i] = (p < BM + 2 * BN);
    src[i] = nullptr; ldsOff[i] = 0; bufMul[i] = 0; planeStep[i] = 0;
    docvt[i] = false; strideB[i] = 0;
    if (!pv[i]) continue;
    if (p < BM) {
      int row = p;
      docvt[i] = false;
      ldsOff[i]   = row * 16;
      bufMul[i]   = A_BUF_BYTES;
      planeStep[i]= BM * 16;
      strideB[i]  = 64;   // 32 bf16 per k-tile
      if (row < n_e - m0)
        src[i] = (const char*)(u + (size_t)(base + m0 + row) * INTER);
      else src[i] = nullptr;
    } else {
      int q = p - BM;
      int col = q >> 1, half = q & 1;
      docvt[i] = true;
      ldsOff[i]   = B_BASE + ((half * 2) * BN + col) * 16;
      bufMul[i]   = B_BUF_BYTES;
      planeStep[i]= BN * 16;
      strideB[i]  = 128;  // 32 f32 per k-tile
      src[i] = (const char*)(dwn + (size_t)(e * HIDDEN + nt * BN + col) * INTER + half * 16);
    }
  }

  float4 rr[2][4];
  auto LOADP = [&](int kt) {
    #pragma unroll
    for (int i = 0; i < 2; ++i) {
      if (!pv[i]) continue;
      if (src[i]) {
        const float4* s = (const float4*)(src[i] + (size_t)kt * strideB[i]);
        rr[i][0] = s[0]; rr[i][1] = s[1]; rr[i][2] = s[2]; rr[i][3] = s[3];
      } else {
        float4 z = make_float4(0.f, 0.f, 0.f, 0.f);
        rr[i][0] = z; rr[i][1] = z; rr[i][2] = z; rr[i][3] = z;
      }
    }
  };
  auto STAGEW = [&](int buf) {
    #pragma unroll
    for (int i = 0; i < 2; ++i) {
      if (!pv[i]) continue;
      char* dst = lds + ldsOff[i] + buf * bufMul[i];
      if (docvt[i]) {
        uint4 w0, w1;
        w0.x = cvt2bf(rr[i][0].x, rr[i][0].y); w0.y = cvt2bf(rr[i][0].z, rr[i][0].w);
        w0.z = cvt2bf(rr[i][1].x, rr[i][1].y); w0.w = cvt2bf(rr[i][1].z, rr[i][1].w);
        w1.x = cvt2bf(rr[i][2].x, rr[i][2].y); w1.y = cvt2bf(rr[i][2].z, rr[i][2].w);
        w1.z = cvt2bf(rr[i][3].x, rr[i][3].y); w1.w = cvt2bf(rr[i][3].z, rr[i][3].w);
        *(uint4*)dst = w0;
        *(uint4*)(dst + planeStep[i]) = w1;
      } else {
        #pragma unroll
        for (int j = 0; j < 4; ++j) {
          uint4 w;
          w.x = __float_as_uint(rr[i][j].x); w.y = __float_as_uint(rr[i][j].y);
          w.z = __float_as_uint(rr[i][j].z); w.w = __float_as_uint(rr[i][j].w);
          *(uint4*)(dst + j * planeStep[i]) = w;
        }
      }
    }
  };

  f32x4 acc[5][5];
  #pragma unroll
  for (int fm = 0; fm < 5; ++fm)
    #pragma unroll
    for (int fn = 0; fn < 5; ++fn)
      acc[fm][fn] = f32x4{0.f, 0.f, 0.f, 0.f};

  const int aoffBase = ((lane >> 4) * BM + wm * 80 + (lane & 15)) * 16;
  const int boffBase = B_BASE + ((lane >> 4) * BN + wn * 80 + (lane & 15)) * 16;

  auto COMP = [&](int buf) {
    const char* ab = lds + buf * A_BUF_BYTES + aoffBase;
    const char* bb = lds + buf * B_BUF_BYTES + boffBase;
    bf16x8 af[5], bfr[5];
    #pragma unroll
    for (int f = 0; f < 5; ++f) af[f]  = *(const bf16x8*)(ab + f * 256);
    #pragma unroll
    for (int f = 0; f < 5; ++f) bfr[f] = *(const bf16x8*)(bb + f * 256);
    #pragma unroll
    for (int fm = 0; fm < 5; ++fm)
      #pragma unroll
      for (int fn = 0; fn < 5; ++fn)
        acc[fm][fn] = __builtin_amdgcn_mfma_f32_16x16x32_bf16(af[fm], bfr[fn], acc[fm][fn], 0, 0, 0);
  };

  LOADP(0);
  STAGEW(0);
  __syncthreads();
  for (int kt = 0; kt < NK; ++kt) {
    if (kt + 1 < NK) LOADP(kt + 1);
    COMP(kt & 1);
    if (kt + 1 < NK) STAGEW((kt + 1) & 1);
    __syncthreads();
  }

  // epilogue: +down_bias, scatter rows to out[pair]
  const int colBase = nt * BN + wn * 80 + (lane & 15);
  const int rowLocal = wm * 80 + ((lane >> 4) * 4);
  #pragma unroll
  for (int fm = 0; fm < 5; ++fm) {
    int aidx[4];
    #pragma unroll
    for (int j = 0; j < 4; ++j) {
      int row = m0 + rowLocal + fm * 16 + j;
      aidx[j] = (row < n_e) ? list[base + row] : -1;
    }
    #pragma unroll
    for (int fn = 0; fn < 5; ++fn) {
      const int colg = colBase + fn * 16;
      const float bias = dbias[e * HIDDEN + colg];
      #pragma unroll
      for (int j = 0; j < 4; ++j) {
        if (aidx[j] >= 0)
          out[(size_t)aidx[j] * HIDDEN + colg] = acc[fm][fn][j] + bias;
      }
    }
  }
}

extern "C" void kernel_launch(void* const* d_in, const int* in_sizes, int n_in,
                              void* d_out, int out_size, void* d_ws, size_t ws_size,
                              hipStream_t stream) {
  const float* t     = (const float*)d_in[0];
  const int*   eidx  = (const int*)d_in[1];
  const float* gup   = (const float*)d_in[2];
  const float* gub   = (const float*)d_in[3];
  const float* dwn   = (const float*)d_in[4];
  const float* dbias = (const float*)d_in[5];
  float* out = (float*)d_out;

  char* ws = (char*)d_ws;
  __hip_bfloat16* u = (__hip_bfloat16*)ws;
  int* meta = (int*)(ws + UBYTES);   // 24 ints
  int* list = meta + 24;             // 2048 ints

  route_count<<<1, 256, 0, stream>>>(eidx, meta);
  route_scatter<<<NPAIR / 256, 256, 0, stream>>>(eidx, meta, list);

  dim3 g1(GUP_ROWS / BN, MT_MAX, NEXP);   // 36 x 7 x 8
  gemm1_swiglu<<<g1, NTHREADS, 0, stream>>>(t, gup, gub, meta, list, u);

  dim3 g2(HIDDEN / BN, MT_MAX, NEXP);     // 18 x 7 x 8
  gemm2_down<<<g2, NTHREADS, 0, stream>>>(u, dwn, dbias, meta, list, out);
}

// Round 3
// 511.042 us; speedup vs baseline: 1.0391x; 1.0391x over previous
//
#include <hip/hip_runtime.h>
#include <hip/hip_bf16.h>

#define HIDDEN   2880
#define INTER    2880
#define NEXP     8
#define GUP_ROWS (2*INTER)   // 5760
#define NPAIR    2048

#define BM 256
#define BN 96
#define BK 32
#define NK (HIDDEN/BK)       // 90
#define NT 256
#define MT_MAX 8             // ceil(2048/256) worst case; extras early-exit

#define A_BUF (BM*BK*2)              // 16384
#define B_BUF (BN*BK*2)              // 6144
#define B_BASE (2*A_BUF)             // 32768
#define LDS_BYTES (2*A_BUF + 2*B_BUF)  // 45056

#define UBYTES ((size_t)NPAIR * INTER * 2)    // u bf16
#define ABYTES ((size_t)NPAIR * HIDDEN * 2)   // gathered A bf16

using bf16x8 = __attribute__((ext_vector_type(8))) short;
using f32x4  = __attribute__((ext_vector_type(4))) float;

__device__ __forceinline__ unsigned cvt2bf(float a, float b) {
  union { __hip_bfloat16 h; unsigned short s; } x, y;
  x.h = __float2bfloat16(a);
  y.h = __float2bfloat16(b);
  return (unsigned)x.s | ((unsigned)y.s << 16);
}

// ---------------- routing ----------------
// meta: [0..7]=counts  [8..15]=offsets  [16..23]=cursor
__global__ void route_count(const int* __restrict__ eidx, int* __restrict__ meta) {
  __shared__ int cnt[NEXP];
  int t = threadIdx.x;
  if (t < NEXP) cnt[t] = 0;
  __syncthreads();
  for (int a = t; a < NPAIR; a += 256) atomicAdd(&cnt[eidx[a]], 1);
  __syncthreads();
  if (t == 0) {
    int off = 0;
    for (int e = 0; e < NEXP; ++e) {
      meta[e] = cnt[e];
      meta[8 + e] = off;
      meta[16 + e] = off;
      off += cnt[e];
    }
  }
}

__global__ void route_scatter(const int* __restrict__ eidx, int* __restrict__ meta,
                              int* __restrict__ list) {
  int a = blockIdx.x * 256 + threadIdx.x;
  int e = eidx[a];
  int pos = atomicAdd(&meta[16 + e], 1);
  list[pos] = a;   // a = token*4 + slot
}

// ---------------- gather A rows to bf16, expert-sorted ----------------
__global__ void gather_a(const float* __restrict__ t, const int* __restrict__ list,
                         __hip_bfloat16* __restrict__ abuf) {
  int i = blockIdx.x;               // pair slot
  int tok = list[i] >> 2;
  const float* src = t + (size_t)tok * HIDDEN;
  char* dst = (char*)(abuf + (size_t)i * HIDDEN);
  for (int c = threadIdx.x * 4; c < HIDDEN; c += 256 * 4) {
    float4 v = *(const float4*)(src + c);
    uint2 w; w.x = cvt2bf(v.x, v.y); w.y = cvt2bf(v.z, v.w);
    *(uint2*)(dst + (size_t)c * 2) = w;
  }
}

// ---------------- GEMM1: h = A @ gup^T + bias ; u = swiglu(h) ----------------
__global__ __launch_bounds__(NT, 2)
void gemm1_swiglu(const __hip_bfloat16* __restrict__ abuf,
                  const float* __restrict__ gup,
                  const float* __restrict__ gub,
                  const int* __restrict__ meta,
                  __hip_bfloat16* __restrict__ u)
{
  const int e  = blockIdx.z;
  const int mt = blockIdx.y;
  const int nt = blockIdx.x;
  const int n_e = meta[e];
  const int m0 = mt * BM;
  if (m0 >= n_e) return;
  const int base = meta[8 + e];

  __shared__ __align__(16) char lds[LDS_BYTES];
  const int tid = threadIdx.x, lane = tid & 63, wid = tid >> 6;
  const int wm = wid >> 1, wn = wid & 1;

  // A piece: one full bf16 row-slice (64B/k-tile) per thread
  const bool aValid = (tid < n_e - m0);
  const char* aSrc = aValid ? (const char*)(abuf + (size_t)(base + m0 + tid) * HIDDEN) : nullptr;
  const int aDst = tid * 16;
  // B piece: threads 0..191, (col, half) — 16 f32 each, cvt to bf16
  const bool hasB = (tid < 2 * BN);
  const int bCol = tid >> 1, bHalf = tid & 1;
  const char* bSrc = hasB ? (const char*)(gup + (size_t)(e * GUP_ROWS + nt * BN + bCol) * HIDDEN + bHalf * 16) : nullptr;
  const int bDst = B_BASE + ((bHalf * 2) * BN + bCol) * 16;

  uint4 ra[4]; float4 rb[4];
  auto LOADP = [&](int kt) {
    if (aSrc) {
      const uint4* s = (const uint4*)(aSrc + (size_t)kt * 64);
      ra[0] = s[0]; ra[1] = s[1]; ra[2] = s[2]; ra[3] = s[3];
    } else {
      uint4 z{0, 0, 0, 0}; ra[0] = z; ra[1] = z; ra[2] = z; ra[3] = z;
    }
    if (bSrc) {
      const float4* s = (const float4*)(bSrc + (size_t)kt * 128);
      rb[0] = s[0]; rb[1] = s[1]; rb[2] = s[2]; rb[3] = s[3];
    }
  };
  auto STAGEW = [&](int buf) {
    char* da = lds + aDst + buf * A_BUF;
    *(uint4*)(da)              = ra[0];
    *(uint4*)(da + BM * 16)    = ra[1];
    *(uint4*)(da + 2 * BM * 16) = ra[2];
    *(uint4*)(da + 3 * BM * 16) = ra[3];
    if (hasB) {
      char* db = lds + bDst + buf * B_BUF;
      uint4 w0, w1;
      w0.x = cvt2bf(rb[0].x, rb[0].y); w0.y = cvt2bf(rb[0].z, rb[0].w);
      w0.z = cvt2bf(rb[1].x, rb[1].y); w0.w = cvt2bf(rb[1].z, rb[1].w);
      w1.x = cvt2bf(rb[2].x, rb[2].y); w1.y = cvt2bf(rb[2].z, rb[2].w);
      w1.z = cvt2bf(rb[3].x, rb[3].y); w1.w = cvt2bf(rb[3].z, rb[3].w);
      *(uint4*)db            = w0;
      *(uint4*)(db + BN * 16) = w1;
    }
  };

  f32x4 acc[8][3];
  #pragma unroll
  for (int fm = 0; fm < 8; ++fm)
    #pragma unroll
    for (int fn = 0; fn < 3; ++fn)
      acc[fm][fn] = f32x4{0.f, 0.f, 0.f, 0.f};

  const int aoff = ((lane >> 4) * BM + wm * 128 + (lane & 15)) * 16;
  const int boff = B_BASE + ((lane >> 4) * BN + wn * 48 + (lane & 15)) * 16;

  auto COMP = [&](int buf) {
    const char* ab = lds + buf * A_BUF + aoff;
    const char* bb = lds + buf * B_BUF + boff;
    bf16x8 af[8], bfr[3];
    #pragma unroll
    for (int f = 0; f < 8; ++f) af[f]  = *(const bf16x8*)(ab + f * 256);
    #pragma unroll
    for (int f = 0; f < 3; ++f) bfr[f] = *(const bf16x8*)(bb + f * 256);
    #pragma unroll
    for (int fm = 0; fm < 8; ++fm)
      #pragma unroll
      for (int fn = 0; fn < 3; ++fn)
        acc[fm][fn] = __builtin_amdgcn_mfma_f32_16x16x32_bf16(af[fm], bfr[fn], acc[fm][fn], 0, 0, 0);
  };

  LOADP(0);
  for (int kt = 0; kt < NK; ++kt) {
    STAGEW(kt & 1);
    __syncthreads();
    __builtin_amdgcn_sched_barrier(0);
    if (kt + 1 < NK) LOADP(kt + 1);
    COMP(kt & 1);
  }

  // epilogue: +bias, swiglu (even col = glu, odd = lin), write u bf16
  const int colBase = nt * BN + wn * 48 + (lane & 15);
  const int rowBase = m0 + wm * 128 + ((lane >> 4) * 4);
  #pragma unroll
  for (int fm = 0; fm < 8; ++fm) {
    #pragma unroll
    for (int fn = 0; fn < 3; ++fn) {
      const int colg = colBase + fn * 16;
      const float bias = gub[e * GUP_ROWS + colg];
      #pragma unroll
      for (int j = 0; j < 4; ++j) {
        float h = acc[fm][fn][j] + bias;
        float other = __shfl_xor(h, 1, 64);
        int row = rowBase + fm * 16 + j;
        if (!(lane & 1)) {
          float xg = fminf(h, 7.0f);
          float xl = fminf(fmaxf(other, -7.0f), 7.0f);
          float og = xg / (1.0f + __expf(-1.702f * xg));
          float uv = og * (xl + 1.0f);
          if (row < n_e)
            u[(size_t)(base + row) * INTER + (colg >> 1)] = __float2bfloat16(uv);
        }
      }
    }
  }
}

// ---------------- GEMM2: y = u @ dwn^T + dbias, scatter ----------------
__global__ __launch_bounds__(NT, 2)
void gemm2_down(const __hip_bfloat16* __restrict__ u,
                const float* __restrict__ dwn,
                const float* __restrict__ dbias,
                const int* __restrict__ meta,
                const int* __restrict__ list,
                float* __restrict__ out)
{
  const int e  = blockIdx.z;
  const int mt = blockIdx.y;
  const int nt = blockIdx.x;
  const int n_e = meta[e];
  const int m0 = mt * BM;
  if (m0 >= n_e) return;
  const int base = meta[8 + e];

  __shared__ __align__(16) char lds[LDS_BYTES];
  const int tid = threadIdx.x, lane = tid & 63, wid = tid >> 6;
  const int wm = wid >> 1, wn = wid & 1;

  const bool aValid = (tid < n_e - m0);
  const char* aSrc = aValid ? (const char*)(u + (size_t)(base + m0 + tid) * INTER) : nullptr;
  const int aDst = tid * 16;
  const bool hasB = (tid < 2 * BN);
  const int bCol = tid >> 1, bHalf = tid & 1;
  const char* bSrc = hasB ? (const char*)(dwn + ((size_t)e * HIDDEN + nt * BN + bCol) * INTER + bHalf * 16) : nullptr;
  const int bDst = B_BASE + ((bHalf * 2) * BN + bCol) * 16;

  uint4 ra[4]; float4 rb[4];
  auto LOADP = [&](int kt) {
    if (aSrc) {
      const uint4* s = (const uint4*)(aSrc + (size_t)kt * 64);
      ra[0] = s[0]; ra[1] = s[1]; ra[2] = s[2]; ra[3] = s[3];
    } else {
      uint4 z{0, 0, 0, 0}; ra[0] = z; ra[1] = z; ra[2] = z; ra[3] = z;
    }
    if (bSrc) {
      const float4* s = (const float4*)(bSrc + (size_t)kt * 128);
      rb[0] = s[0]; rb[1] = s[1]; rb[2] = s[2]; rb[3] = s[3];
    }
  };
  auto STAGEW = [&](int buf) {
    char* da = lds + aDst + buf * A_BUF;
    *(uint4*)(da)               = ra[0];
    *(uint4*)(da + BM * 16)     = ra[1];
    *(uint4*)(da + 2 * BM * 16) = ra[2];
    *(uint4*)(da + 3 * BM * 16) = ra[3];
    if (hasB) {
      char* db = lds + bDst + buf * B_BUF;
      uint4 w0, w1;
      w0.x = cvt2bf(rb[0].x, rb[0].y); w0.y = cvt2bf(rb[0].z, rb[0].w);
      w0.z = cvt2bf(rb[1].x, rb[1].y); w0.w = cvt2bf(rb[1].z, rb[1].w);
      w1.x = cvt2bf(rb[2].x, rb[2].y); w1.y = cvt2bf(rb[2].z, rb[2].w);
      w1.z = cvt2bf(rb[3].x, rb[3].y); w1.w = cvt2bf(rb[3].z, rb[3].w);
      *(uint4*)db             = w0;
      *(uint4*)(db + BN * 16) = w1;
    }
  };

  f32x4 acc[8][3];
  #pragma unroll
  for (int fm = 0; fm < 8; ++fm)
    #pragma unroll
    for (int fn = 0; fn < 3; ++fn)
      acc[fm][fn] = f32x4{0.f, 0.f, 0.f, 0.f};

  const int aoff = ((lane >> 4) * BM + wm * 128 + (lane & 15)) * 16;
  const int boff = B_BASE + ((lane >> 4) * BN + wn * 48 + (lane & 15)) * 16;

  auto COMP = [&](int buf) {
    const char* ab = lds + buf * A_BUF + aoff;
    const char* bb = lds + buf * B_BUF + boff;
    bf16x8 af[8], bfr[3];
    #pragma unroll
    for (int f = 0; f < 8; ++f) af[f]  = *(const bf16x8*)(ab + f * 256);
    #pragma unroll
    for (int f = 0; f < 3; ++f) bfr[f] = *(const bf16x8*)(bb + f * 256);
    #pragma unroll
    for (int fm = 0; fm < 8; ++fm)
      #pragma unroll
      for (int fn = 0; fn < 3; ++fn)
        acc[fm][fn] = __builtin_amdgcn_mfma_f32_16x16x32_bf16(af[fm], bfr[fn], acc[fm][fn], 0, 0, 0);
  };

  LOADP(0);
  for (int kt = 0; kt < NK; ++kt) {
    STAGEW(kt & 1);
    __syncthreads();
    __builtin_amdgcn_sched_barrier(0);
    if (kt + 1 < NK) LOADP(kt + 1);
    COMP(kt & 1);
  }

  const int colBase = nt * BN + wn * 48 + (lane & 15);
  const int rowLocal = wm * 128 + ((lane >> 4) * 4);
  #pragma unroll
  for (int fm = 0; fm < 8; ++fm) {
    int aidx[4];
    #pragma unroll
    for (int j = 0; j < 4; ++j) {
      int row = m0 + rowLocal + fm * 16 + j;
      aidx[j] = (row < n_e) ? list[base + row] : -1;
    }
    #pragma unroll
    for (int fn = 0; fn < 3; ++fn) {
      const int colg = colBase + fn * 16;
      const float bias = dbias[e * HIDDEN + colg];
      #pragma unroll
      for (int j = 0; j < 4; ++j) {
        if (aidx[j] >= 0)
          out[(size_t)aidx[j] * HIDDEN + colg] = acc[fm][fn][j] + bias;
      }
    }
  }
}

extern "C" void kernel_launch(void* const* d_in, const int* in_sizes, int n_in,
                              void* d_out, int out_size, void* d_ws, size_t ws_size,
                              hipStream_t stream) {
  const float* t     = (const float*)d_in[0];
  const int*   eidx  = (const int*)d_in[1];
  const float* gup   = (const float*)d_in[2];
  const float* gub   = (const float*)d_in[3];
  const float* dwn   = (const float*)d_in[4];
  const float* dbias = (const float*)d_in[5];
  float* out = (float*)d_out;

  char* ws = (char*)d_ws;
  __hip_bfloat16* u    = (__hip_bfloat16*)ws;
  __hip_bfloat16* abuf = (__hip_bfloat16*)(ws + UBYTES);
  int* meta = (int*)(ws + UBYTES + ABYTES);   // 24 ints
  int* list = meta + 24;                      // 2048 ints

  route_count<<<1, 256, 0, stream>>>(eidx, meta);
  route_scatter<<<NPAIR / 256, 256, 0, stream>>>(eidx, meta, list);
  gather_a<<<NPAIR, 256, 0, stream>>>(t, list, abuf);

  dim3 g1(GUP_ROWS / BN, MT_MAX, NEXP);   // 60 x 8 x 8
  gemm1_swiglu<<<g1, NT, 0, stream>>>(abuf, gup, gub, meta, u);

  dim3 g2(HIDDEN / BN, MT_MAX, NEXP);     // 30 x 8 x 8
  gemm2_down<<<g2, NT, 0, stream>>>(u, dwn, dbias, meta, list, out);
}